// Round 15
// baseline (120.525 us; speedup 1.0000x reference)
//
#include <hip/hip_runtime.h>

#define NN   50000
#define NE   800000          // == 256*3125 exactly
#define CAP  48              // max stored in-degree (Poisson(16): P(>48) ~ 1e-12)
#define NPG  6250            // NN / 8 groups
#define EPB  3125            // edges per bin block
#define SEG  576             // per-(group,block) slab (mean 390, +10 sigma)

#define BIN_BLOCKS  256
#define CVT_BLOCKS  (3125 + 128)
#define ZERO_BLOCKS 196      // 196*256 = 50176 >= NN
#define SCAT_BLOCKS 2048

typedef __attribute__((ext_vector_type(8))) short bf16x8;
typedef __attribute__((ext_vector_type(4))) unsigned short u16x4;
typedef __attribute__((ext_vector_type(4))) float f32x4;

__device__ __forceinline__ unsigned short f2b(float f) {   // round-to-nearest-even
    unsigned int u = __builtin_bit_cast(unsigned int, f);
    u += 0x7FFFu + ((u >> 16) & 1u);
    return (unsigned short)(u >> 16);
}
__device__ __forceinline__ float b2f_lo(unsigned int u) {
    return __builtin_bit_cast(float, u << 16);
}
__device__ __forceinline__ float b2f_hi(unsigned int u) {
    return __builtin_bit_cast(float, u & 0xFFFF0000u);
}
// ---- software e4m3 codec (self-consistent; exact RNE via 2^±120 scaling) ----
__device__ __forceinline__ unsigned e4m3_enc(float f) {
    float g = f * 0x1p-120f;                       // e4m3 grid -> f32 bits 22:20
    unsigned u = __builtin_bit_cast(unsigned, g);
    u += 0x7FFFFu + ((u >> 20) & 1u);              // RNE drop 20 bits
    return ((u >> 20) & 0x7Fu) | ((u >> 24) & 0x80u);
}
__device__ __forceinline__ float e4m3_dec(unsigned b) {
    unsigned bits = ((b & 0x80u) << 24) | ((b & 0x7Fu) << 20);
    return __builtin_bit_cast(float, bits) * 0x1p120f;
}

// ---------------------------------------------------------------------------
// prep = pass-1 edge binning + bf16 conversions + cursor zeroing (unchanged)
// ---------------------------------------------------------------------------
__global__ __launch_bounds__(256) void prep_kernel(const int* __restrict__ src,
                                                   const int* __restrict__ dst,
                                                   int* __restrict__ bcnt,
                                                   unsigned* __restrict__ stage,
                                                   const float* __restrict__ x,
                                                   const float* __restrict__ W1l,
                                                   const float* __restrict__ W1r,
                                                   const float* __restrict__ W2l,
                                                   const float* __restrict__ W2r,
                                                   unsigned short* __restrict__ xb,
                                                   unsigned short* __restrict__ Bt1,
                                                   unsigned short* __restrict__ Bt2,
                                                   int* __restrict__ cursor) {
    if (blockIdx.x < BIN_BLOCKS) {
        __shared__ int cnt[16][8];
        __shared__ int repoff[16][8];
        const int tid = threadIdx.x;
        const int b   = blockIdx.x;
        const int r   = tid >> 4;                 // 16 replicas
        if (tid < 128) ((int*)cnt)[tid] = 0;
        __syncthreads();

        unsigned recs[13], metas[13];
#pragma unroll
        for (int it = 0; it < 13; ++it) {
            const int i = it * 256 + tid;
            metas[it] = 0xFFFFFFFFu;
            if (i < EPB) {
                const int e = b * EPB + i;
                const int s = src[e], d = dst[e];
                const int g = d / NPG;
                const int dloc = d - g * NPG;
                const int slot = atomicAdd(&cnt[r][g], 1);
                recs[it]  = ((unsigned)dloc << 16) | (unsigned)s;
                metas[it] = ((unsigned)r << 20) | ((unsigned)g << 16) | (unsigned)slot;
            }
        }
        __syncthreads();
        if (tid < 8) {
            int off = 0;
#pragma unroll
            for (int rr = 0; rr < 16; ++rr) { repoff[rr][tid] = off; off += cnt[rr][tid]; }
            bcnt[tid * 256 + b] = off;            // plain store, no atomics
        }
        __syncthreads();
#pragma unroll
        for (int it = 0; it < 13; ++it) {
            if (metas[it] != 0xFFFFFFFFu) {
                const int rr   = metas[it] >> 20;
                const int g    = (metas[it] >> 16) & 7;
                const int slot = metas[it] & 0xFFFF;
                const int pos  = repoff[rr][g] + slot;
                if (pos < SEG) stage[((g << 8) + b) * SEG + pos] = recs[it];
            }
        }
    } else if (blockIdx.x < BIN_BLOCKS + 3125) {
        int i = (blockIdx.x - BIN_BLOCKS) * 256 + threadIdx.x;   // 8-elem chunk
        const float4* p = reinterpret_cast<const float4*>(x) + (size_t)i * 2;
        float4 a = p[0], b = p[1];
        uint4 u;
        u.x = (unsigned)f2b(a.x) | ((unsigned)f2b(a.y) << 16);
        u.y = (unsigned)f2b(a.z) | ((unsigned)f2b(a.w) << 16);
        u.z = (unsigned)f2b(b.x) | ((unsigned)f2b(b.y) << 16);
        u.w = (unsigned)f2b(b.z) | ((unsigned)f2b(b.w) << 16);
        reinterpret_cast<uint4*>(xb)[i] = u;
    } else if (blockIdx.x < BIN_BLOCKS + CVT_BLOCKS) {
        int t = (blockIdx.x - BIN_BLOCKS - 3125) * 256 + threadIdx.x;
        if (t < 32768) {                              // 128 cols x 256 k
            int c = t >> 8, k = t & 255;
            float v = (k < 128) ? W1l[k * 128 + c] : W1r[(k - 128) * 128 + c];
            Bt1[c * 256 + k] = f2b(v);
        }
        if (t < 16384) {                              // 128 cols x 128 k
            int c = t >> 7, k = t & 127;
            float v = (c < 64) ? W2l[k * 64 + c] : W2r[k * 64 + (c - 64)];
            Bt2[c * 128 + k] = f2b(v);
        }
    } else {
        int i = (blockIdx.x - BIN_BLOCKS - CVT_BLOCKS) * 256 + threadIdx.x;
        if (i < NN) cursor[i] = 0;
    }
}

// ---------------------------------------------------------------------------
// pass-2 scatter: (g = blockIdx&7, b = blockIdx>>3) -> cursor/col, XCD-local.
// ---------------------------------------------------------------------------
__global__ __launch_bounds__(256) void scatter_kernel(const int* __restrict__ bcnt,
                                                      const unsigned* __restrict__ stage,
                                                      int* __restrict__ cursor,
                                                      unsigned short* __restrict__ col) {
    const int g = blockIdx.x & 7;
    const int b = blockIdx.x >> 3;                 // 0..255
    int cnt = bcnt[g * 256 + b];
    if (cnt > SEG) cnt = SEG;
    const unsigned* sp = stage + (size_t)((g << 8) + b) * SEG;
    const int n0 = g * NPG;
    for (int i = threadIdx.x; i < cnt; i += 256) {
        unsigned rec = sp[i];
        int d = n0 + (int)(rec >> 16);
        int p = atomicAdd(&cursor[d], 1);
        if (p < CAP) col[d * CAP + p] = (unsigned short)(rec & 0xFFFFu);
    }
}

// ---------------------------------------------------------------------------
// FULLY FUSED layer-1 + layer-2 transform. XCD-aligned grid: 8 groups x 98
// blocks; group g = blockIdx&7 owns dst rows [g*NPG, (g+1)*NPG) so cursor/col
// reads hit the L2 that scatter wrote them to.
//  A: gather-mean 64 rows -> LDS [m1|x] (4-wide unroll, ushort cols)
//  B: C1 = A @ Bt1^T (K=256);  C: h=relu(C1+b1) -> Hs (LDS)
//  D: C2 = Hs @ Bt2^T (K=128); cols<64 -> hl8 fp8 e4m3; cols>=64 -> hrb bf16.
// ---------------------------------------------------------------------------
__global__ __launch_bounds__(256) void agg_gemm12(const unsigned short* __restrict__ xb,
                                                  const int* __restrict__ cursor,
                                                  const unsigned short* __restrict__ col,
                                                  const unsigned short* __restrict__ Bt1,
                                                  const unsigned short* __restrict__ Bt2,
                                                  const float* __restrict__ b1,
                                                  unsigned char* __restrict__ hl8,
                                                  unsigned short* __restrict__ hrb) {
    constexpr int LDA = 264;                       // 256 + 8 pad
    constexpr int LDH = 136;                       // 128 + 8 pad
    __shared__ unsigned short As[64 * LDA];        // 33.8 KB; Hs aliases front

    const int g     = blockIdx.x & 7;
    const int lbase = (blockIdx.x >> 3) * 64;      // local row base within group
    const int gbase = g * NPG + lbase;
    const int tid   = threadIdx.x;
    const int l     = tid & 15;                    // 8 dims (16B) per lane
    const int sub   = tid >> 4;                    // 16 rows at a time

    const uint4* fp = reinterpret_cast<const uint4*>(xb);

    // ---- phase A: gather (4-wide unroll, ushort cols) ----
    for (int gq = 0; gq < 4; ++gq) {
        const int r  = gq * 16 + sub;              // 0..63
        const int gn = gbase + r;
        float a0 = 0.f, a1 = 0.f, a2 = 0.f, a3 = 0.f,
              a4 = 0.f, a5 = 0.f, a6 = 0.f, a7 = 0.f;
        uint4 xrow = make_uint4(0, 0, 0, 0);
        if (lbase + r < NPG) {
            int len = cursor[gn];
            len = (len > CAP) ? CAP : len;
            const unsigned short* cl = col + gn * CAP;
            int j = 0;
            for (; j + 4 <= len; j += 4) {
                u16x4 c4 = *reinterpret_cast<const u16x4*>(cl + j);
                uint4 v0 = fp[(int)c4[0] * 16 + l];
                uint4 v1 = fp[(int)c4[1] * 16 + l];
                uint4 v2 = fp[(int)c4[2] * 16 + l];
                uint4 v3 = fp[(int)c4[3] * 16 + l];
                a0 += (b2f_lo(v0.x) + b2f_lo(v1.x)) + (b2f_lo(v2.x) + b2f_lo(v3.x));
                a1 += (b2f_hi(v0.x) + b2f_hi(v1.x)) + (b2f_hi(v2.x) + b2f_hi(v3.x));
                a2 += (b2f_lo(v0.y) + b2f_lo(v1.y)) + (b2f_lo(v2.y) + b2f_lo(v3.y));
                a3 += (b2f_hi(v0.y) + b2f_hi(v1.y)) + (b2f_hi(v2.y) + b2f_hi(v3.y));
                a4 += (b2f_lo(v0.z) + b2f_lo(v1.z)) + (b2f_lo(v2.z) + b2f_lo(v3.z));
                a5 += (b2f_hi(v0.z) + b2f_hi(v1.z)) + (b2f_hi(v2.z) + b2f_hi(v3.z));
                a6 += (b2f_lo(v0.w) + b2f_lo(v1.w)) + (b2f_lo(v2.w) + b2f_lo(v3.w));
                a7 += (b2f_hi(v0.w) + b2f_hi(v1.w)) + (b2f_hi(v2.w) + b2f_hi(v3.w));
            }
            for (; j < len; ++j) {
                uint4 v0 = fp[(int)cl[j] * 16 + l];
                a0 += b2f_lo(v0.x);  a1 += b2f_hi(v0.x);
                a2 += b2f_lo(v0.y);  a3 += b2f_hi(v0.y);
                a4 += b2f_lo(v0.z);  a5 += b2f_hi(v0.z);
                a6 += b2f_lo(v0.w);  a7 += b2f_hi(v0.w);
            }
            const float inv = 1.0f / fmaxf((float)len, 1.0f);
            a0 *= inv; a1 *= inv; a2 *= inv; a3 *= inv;
            a4 *= inv; a5 *= inv; a6 *= inv; a7 *= inv;
            xrow = fp[gn * 16 + l];
        }
        uint4 u;
        u.x = (unsigned)f2b(a0) | ((unsigned)f2b(a1) << 16);
        u.y = (unsigned)f2b(a2) | ((unsigned)f2b(a3) << 16);
        u.z = (unsigned)f2b(a4) | ((unsigned)f2b(a5) << 16);
        u.w = (unsigned)f2b(a6) | ((unsigned)f2b(a7) << 16);
        *reinterpret_cast<uint4*>(&As[r * LDA + l * 8])       = u;
        *reinterpret_cast<uint4*>(&As[r * LDA + 128 + l * 8]) = xrow;
    }
    __syncthreads();

    const int wid  = tid >> 6, lane = tid & 63;
    const int lr   = lane & 15;
    const int lk   = (lane >> 4) * 8;
    const int ccol = lane & 15;
    const int ri   = (lane >> 4) * 4;

    // ---- phase B: GEMM1, K=256 ----
    f32x4 acc[4][2];
#pragma unroll
    for (int t = 0; t < 4; ++t) {
        acc[t][0] = (f32x4){0.f, 0.f, 0.f, 0.f};
        acc[t][1] = (f32x4){0.f, 0.f, 0.f, 0.f};
    }
    for (int ks = 0; ks < 8; ++ks) {
        const int k = ks * 32 + lk;
        bf16x8 b0 = *reinterpret_cast<const bf16x8*>(Bt1 + (size_t)(wid * 32 + lr) * 256 + k);
        bf16x8 b1 = *reinterpret_cast<const bf16x8*>(Bt1 + (size_t)(wid * 32 + 16 + lr) * 256 + k);
#pragma unroll
        for (int t = 0; t < 4; ++t) {
            bf16x8 a = *reinterpret_cast<const bf16x8*>(&As[(t * 16 + lr) * LDA + k]);
            acc[t][0] = __builtin_amdgcn_mfma_f32_16x16x32_bf16(a, b0, acc[t][0], 0, 0, 0);
            acc[t][1] = __builtin_amdgcn_mfma_f32_16x16x32_bf16(a, b1, acc[t][1], 0, 0, 0);
        }
    }
    __syncthreads();                               // all As reads complete

    // ---- phase C: h = relu(C1 + b1) -> Hs (reuse As memory) ----
    unsigned short* Hs = As;
#pragma unroll
    for (int t = 0; t < 4; ++t) {
#pragma unroll
        for (int f = 0; f < 2; ++f) {
            const int colg = wid * 32 + f * 16 + ccol;
            const float bv = b1[colg];
#pragma unroll
            for (int i = 0; i < 4; ++i) {
                Hs[(t * 16 + ri + i) * LDH + colg] = f2b(fmaxf(acc[t][f][i] + bv, 0.f));
            }
        }
    }
    __syncthreads();

    // ---- phase D: GEMM2, K=128 from Hs; B streamed from L2-hot Bt2 ----
    f32x4 acc2[4][2];
#pragma unroll
    for (int t = 0; t < 4; ++t) {
        acc2[t][0] = (f32x4){0.f, 0.f, 0.f, 0.f};
        acc2[t][1] = (f32x4){0.f, 0.f, 0.f, 0.f};
    }
    for (int ks = 0; ks < 4; ++ks) {
        const int k = ks * 32 + lk;
        bf16x8 b0 = *reinterpret_cast<const bf16x8*>(Bt2 + (size_t)(wid * 32 + lr) * 128 + k);
        bf16x8 b1 = *reinterpret_cast<const bf16x8*>(Bt2 + (size_t)(wid * 32 + 16 + lr) * 128 + k);
#pragma unroll
        for (int t = 0; t < 4; ++t) {
            bf16x8 a = *reinterpret_cast<const bf16x8*>(&Hs[(t * 16 + lr) * LDH + k]);
            acc2[t][0] = __builtin_amdgcn_mfma_f32_16x16x32_bf16(a, b0, acc2[t][0], 0, 0, 0);
            acc2[t][1] = __builtin_amdgcn_mfma_f32_16x16x32_bf16(a, b1, acc2[t][1], 0, 0, 0);
        }
    }

#pragma unroll
    for (int t = 0; t < 4; ++t) {
#pragma unroll
        for (int f = 0; f < 2; ++f) {
            const int colg = wid * 32 + f * 16 + ccol;
#pragma unroll
            for (int i = 0; i < 4; ++i) {
                const int lrow = lbase + t * 16 + ri + i;
                if (lrow < NPG) {
                    const int gn = g * NPG + lrow;
                    float v = acc2[t][f][i];
                    if (colg < 64) hl8[(size_t)gn * 64 + colg] = (unsigned char)e4m3_enc(v);
                    else           hrb[(size_t)gn * 64 + (colg - 64)] = f2b(v);
                }
            }
        }
    }
}

// ---------------------------------------------------------------------------
// layer-2 aggregation: out[n] = mean(hl8[nbrs]) + hrb[n] + b2.
// XCD-aligned grid 8 x 196. 8 lanes/node x 8 dims (uint2 fp8), 4-wide unroll.
// ---------------------------------------------------------------------------
__global__ __launch_bounds__(256) void agg2_kernel(const unsigned char* __restrict__ hl8,
                                                   const int* __restrict__ cursor,
                                                   const unsigned short* __restrict__ col,
                                                   const unsigned short* __restrict__ hrb,
                                                   const float* __restrict__ b2,
                                                   float* __restrict__ outf) {
    const int g    = blockIdx.x & 7;
    const int lrow = (blockIdx.x >> 3) * 32 + (threadIdx.x >> 3);
    const int l    = threadIdx.x & 7;
    if (lrow >= NPG) return;
    const int n = g * NPG + lrow;
    int len = cursor[n];
    len = (len > CAP) ? CAP : len;
    float a0 = 0.f, a1 = 0.f, a2 = 0.f, a3 = 0.f, a4 = 0.f, a5 = 0.f, a6 = 0.f, a7 = 0.f;
    const uint2* fp = reinterpret_cast<const uint2*>(hl8);
    const unsigned short* cl = col + n * CAP;

    int j = 0;
    for (; j + 4 <= len; j += 4) {
        u16x4 c4 = *reinterpret_cast<const u16x4*>(cl + j);
        uint2 v0 = fp[(int)c4[0] * 8 + l];
        uint2 v1 = fp[(int)c4[1] * 8 + l];
        uint2 v2 = fp[(int)c4[2] * 8 + l];
        uint2 v3 = fp[(int)c4[3] * 8 + l];
        a0 += (e4m3_dec(v0.x & 0xFF) + e4m3_dec(v1.x & 0xFF))
            + (e4m3_dec(v2.x & 0xFF) + e4m3_dec(v3.x & 0xFF));
        a1 += (e4m3_dec((v0.x >> 8) & 0xFF) + e4m3_dec((v1.x >> 8) & 0xFF))
            + (e4m3_dec((v2.x >> 8) & 0xFF) + e4m3_dec((v3.x >> 8) & 0xFF));
        a2 += (e4m3_dec((v0.x >> 16) & 0xFF) + e4m3_dec((v1.x >> 16) & 0xFF))
            + (e4m3_dec((v2.x >> 16) & 0xFF) + e4m3_dec((v3.x >> 16) & 0xFF));
        a3 += (e4m3_dec(v0.x >> 24) + e4m3_dec(v1.x >> 24))
            + (e4m3_dec(v2.x >> 24) + e4m3_dec(v3.x >> 24));
        a4 += (e4m3_dec(v0.y & 0xFF) + e4m3_dec(v1.y & 0xFF))
            + (e4m3_dec(v2.y & 0xFF) + e4m3_dec(v3.y & 0xFF));
        a5 += (e4m3_dec((v0.y >> 8) & 0xFF) + e4m3_dec((v1.y >> 8) & 0xFF))
            + (e4m3_dec((v2.y >> 8) & 0xFF) + e4m3_dec((v3.y >> 8) & 0xFF));
        a6 += (e4m3_dec((v0.y >> 16) & 0xFF) + e4m3_dec((v1.y >> 16) & 0xFF))
            + (e4m3_dec((v2.y >> 16) & 0xFF) + e4m3_dec((v3.y >> 16) & 0xFF));
        a7 += (e4m3_dec(v0.y >> 24) + e4m3_dec(v1.y >> 24))
            + (e4m3_dec(v2.y >> 24) + e4m3_dec(v3.y >> 24));
    }
    for (; j < len; ++j) {
        uint2 v0 = fp[(int)cl[j] * 8 + l];
        a0 += e4m3_dec(v0.x & 0xFF);         a1 += e4m3_dec((v0.x >> 8) & 0xFF);
        a2 += e4m3_dec((v0.x >> 16) & 0xFF); a3 += e4m3_dec(v0.x >> 24);
        a4 += e4m3_dec(v0.y & 0xFF);         a5 += e4m3_dec((v0.y >> 8) & 0xFF);
        a6 += e4m3_dec((v0.y >> 16) & 0xFF); a7 += e4m3_dec(v0.y >> 24);
    }
    const float inv = 1.0f / fmaxf((float)len, 1.0f);
    uint4 hv = reinterpret_cast<const uint4*>(hrb)[(size_t)n * 8 + l];
    const float4* bp = reinterpret_cast<const float4*>(b2 + l * 8);
    float4 bv0 = bp[0], bv1 = bp[1];
    float4 o0 = make_float4(a0 * inv + b2f_lo(hv.x) + bv0.x,
                            a1 * inv + b2f_hi(hv.x) + bv0.y,
                            a2 * inv + b2f_lo(hv.y) + bv0.z,
                            a3 * inv + b2f_hi(hv.y) + bv0.w);
    float4 o1 = make_float4(a4 * inv + b2f_lo(hv.z) + bv1.x,
                            a5 * inv + b2f_hi(hv.z) + bv1.y,
                            a6 * inv + b2f_lo(hv.w) + bv1.z,
                            a7 * inv + b2f_hi(hv.w) + bv1.w);
    float4* op = reinterpret_cast<float4*>(outf + (size_t)n * 64) + l * 2;
    op[0] = o0; op[1] = o1;
}

// ---------------------------------------------------------------------------
extern "C" void kernel_launch(void* const* d_in, const int* in_sizes, int n_in,
                              void* d_out, int out_size, void* d_ws, size_t ws_size,
                              hipStream_t stream) {
    const float* x   = (const float*)d_in[0];
    const int*   ei  = (const int*)d_in[1];
    const float* W1l = (const float*)d_in[2];
    const float* b1  = (const float*)d_in[3];
    const float* W1r = (const float*)d_in[4];
    const float* W2l = (const float*)d_in[5];
    const float* b2  = (const float*)d_in[6];
    const float* W2r = (const float*)d_in[7];

    const int* src = ei;
    const int* dst = ei + NE;

    // workspace layout (bytes), total ~48.3 MB:
    // [cursor NN]                  0         .. 200,000   (zeroed by prep tail blocks)
    // [bcnt 2048]                  200,000   .. 208,192
    // [col NN*CAP ushort]          208,384   .. 5,008,384
    // [xb  NN*128 bf16]            9,808,384 .. 22,608,384
    // [hl8 NN*64 fp8]              22,608,384.. 25,808,384
    // [hrb NN*64 bf16]             29,008,384.. 35,408,384
    // [stage 8*256*SEG u32]        35,408,384.. 48,208,384  (dead after scatter)
    // [Bt1 128*256 bf16]           48,208,384.. 48,273,920
    // [Bt2 128*128 bf16]           48,273,920.. 48,306,688
    char* ws = (char*)d_ws;
    int* cursor = (int*)ws;
    int* bcnt   = (int*)(ws + 200000);
    unsigned short* col = (unsigned short*)(ws + 208384);
    unsigned short* xb  = (unsigned short*)(ws + 9808384);
    unsigned char*  hl8 = (unsigned char*)(ws + 22608384);
    unsigned short* hrb = (unsigned short*)(ws + 29008384);
    unsigned*       stage = (unsigned*)(ws + 35408384);
    unsigned short* Bt1 = (unsigned short*)(ws + 48208384);
    unsigned short* Bt2 = (unsigned short*)(ws + 48273920);
    float* outp = (float*)d_out;

    prep_kernel<<<BIN_BLOCKS + CVT_BLOCKS + ZERO_BLOCKS, 256, 0, stream>>>(
        src, dst, bcnt, stage, x, W1l, W1r, W2l, W2r, xb, Bt1, Bt2, cursor);
    scatter_kernel<<<SCAT_BLOCKS, 256, 0, stream>>>(bcnt, stage, cursor, col);

    // ----- fused layer-1 + layer-2 transform, XCD-aligned grid (8 x 98) -----
    agg_gemm12<<<8 * 98, 256, 0, stream>>>(xb, cursor, col, Bt1, Bt2, b1, hl8, hrb);

    // ----- layer-2 aggregation, XCD-aligned grid (8 x 196) -----
    agg2_kernel<<<8 * 196, 256, 0, stream>>>(hl8, cursor, col, hrb, b2, outp);
}

// Round 16
// 114.208 us; speedup vs baseline: 1.0553x; 1.0553x over previous
//
#include <hip/hip_runtime.h>

#define NN   50000
#define NE   800000          // == 256*3125 exactly
#define CAP  48              // max stored in-degree (Poisson(16): P(>48) ~ 1e-12)
#define NPG  6250            // NN / 8 groups
#define EPB  3125            // edges per bin block
#define SEG  576             // per-(group,block) slab (mean 390, +10 sigma)

#define BIN_BLOCKS  256
#define ZERO_BLOCKS 196      // 196*256 = 50176 >= NN
#define SCAT_BLOCKS 2048
#define CVT_BLOCKS  (3125 + 128)

typedef __attribute__((ext_vector_type(8))) short bf16x8;
typedef __attribute__((ext_vector_type(4))) unsigned short u16x4;
typedef __attribute__((ext_vector_type(4))) float f32x4;

__device__ __forceinline__ unsigned short f2b(float f) {   // round-to-nearest-even
    unsigned int u = __builtin_bit_cast(unsigned int, f);
    u += 0x7FFFu + ((u >> 16) & 1u);
    return (unsigned short)(u >> 16);
}
__device__ __forceinline__ float b2f_lo(unsigned int u) {
    return __builtin_bit_cast(float, u << 16);
}
__device__ __forceinline__ float b2f_hi(unsigned int u) {
    return __builtin_bit_cast(float, u & 0xFFFF0000u);
}

// ---------------------------------------------------------------------------
// prep = pass-1 edge binning (blocks [0,BIN)) + cursor zeroing (rest).
// Bin: ZERO global atomics; fixed slab per dst-group; 16-replica LDS counters.
// ---------------------------------------------------------------------------
__global__ __launch_bounds__(256) void prep_kernel(const int* __restrict__ src,
                                                   const int* __restrict__ dst,
                                                   int* __restrict__ bcnt,
                                                   unsigned* __restrict__ stage,
                                                   int* __restrict__ cursor) {
    if (blockIdx.x < BIN_BLOCKS) {
        __shared__ int cnt[16][8];
        __shared__ int repoff[16][8];
        const int tid = threadIdx.x;
        const int b   = blockIdx.x;
        const int r   = tid >> 4;                 // 16 replicas
        if (tid < 128) ((int*)cnt)[tid] = 0;
        __syncthreads();

        unsigned recs[13], metas[13];
#pragma unroll
        for (int it = 0; it < 13; ++it) {
            const int i = it * 256 + tid;
            metas[it] = 0xFFFFFFFFu;
            if (i < EPB) {
                const int e = b * EPB + i;
                const int s = src[e], d = dst[e];
                const int g = d / NPG;
                const int dloc = d - g * NPG;
                const int slot = atomicAdd(&cnt[r][g], 1);
                recs[it]  = ((unsigned)dloc << 16) | (unsigned)s;
                metas[it] = ((unsigned)r << 20) | ((unsigned)g << 16) | (unsigned)slot;
            }
        }
        __syncthreads();
        if (tid < 8) {
            int off = 0;
#pragma unroll
            for (int rr = 0; rr < 16; ++rr) { repoff[rr][tid] = off; off += cnt[rr][tid]; }
            bcnt[tid * 256 + b] = off;            // plain store, no atomics
        }
        __syncthreads();
#pragma unroll
        for (int it = 0; it < 13; ++it) {
            if (metas[it] != 0xFFFFFFFFu) {
                const int rr   = metas[it] >> 20;
                const int g    = (metas[it] >> 16) & 7;
                const int slot = metas[it] & 0xFFFF;
                const int pos  = repoff[rr][g] + slot;
                if (pos < SEG) stage[((g << 8) + b) * SEG + pos] = recs[it];
            }
        }
    } else {
        int i = (blockIdx.x - BIN_BLOCKS) * 256 + threadIdx.x;
        if (i < NN) cursor[i] = 0;
    }
}

// ---------------------------------------------------------------------------
// pass-2 scatter (blocks [0,SCAT)) + bf16 conversions (rest, co-launched —
// cvt streaming hides under the scatter's atomic latency; no dependency).
// scatter: (g = blockIdx&7, b = blockIdx>>3) -> cursor/col (ushort), XCD-local.
// ---------------------------------------------------------------------------
__global__ __launch_bounds__(256) void scatter_kernel(const int* __restrict__ bcnt,
                                                      const unsigned* __restrict__ stage,
                                                      int* __restrict__ cursor,
                                                      unsigned short* __restrict__ col,
                                                      const float* __restrict__ x,
                                                      const float* __restrict__ W1l,
                                                      const float* __restrict__ W1r,
                                                      const float* __restrict__ W2l,
                                                      const float* __restrict__ W2r,
                                                      unsigned short* __restrict__ xb,
                                                      unsigned short* __restrict__ Bt1,
                                                      unsigned short* __restrict__ Bt2) {
    if (blockIdx.x < SCAT_BLOCKS) {
        const int g = blockIdx.x & 7;
        const int b = blockIdx.x >> 3;                 // 0..255
        int cnt = bcnt[g * 256 + b];
        if (cnt > SEG) cnt = SEG;
        const unsigned* sp = stage + (size_t)((g << 8) + b) * SEG;
        const int n0 = g * NPG;
        for (int i = threadIdx.x; i < cnt; i += 256) {
            unsigned rec = sp[i];
            int d = n0 + (int)(rec >> 16);
            int p = atomicAdd(&cursor[d], 1);
            if (p < CAP) col[d * CAP + p] = (unsigned short)(rec & 0xFFFFu);
        }
    } else if (blockIdx.x < SCAT_BLOCKS + 3125) {
        int i = (blockIdx.x - SCAT_BLOCKS) * 256 + threadIdx.x;   // 8-elem chunk
        const float4* p = reinterpret_cast<const float4*>(x) + (size_t)i * 2;
        float4 a = p[0], b = p[1];
        uint4 u;
        u.x = (unsigned)f2b(a.x) | ((unsigned)f2b(a.y) << 16);
        u.y = (unsigned)f2b(a.z) | ((unsigned)f2b(a.w) << 16);
        u.z = (unsigned)f2b(b.x) | ((unsigned)f2b(b.y) << 16);
        u.w = (unsigned)f2b(b.z) | ((unsigned)f2b(b.w) << 16);
        reinterpret_cast<uint4*>(xb)[i] = u;
    } else {
        int t = (blockIdx.x - SCAT_BLOCKS - 3125) * 256 + threadIdx.x;
        if (t < 32768) {                              // 128 cols x 256 k
            int c = t >> 8, k = t & 255;
            float v = (k < 128) ? W1l[k * 128 + c] : W1r[(k - 128) * 128 + c];
            Bt1[c * 256 + k] = f2b(v);
        }
        if (t < 16384) {                              // 128 cols x 128 k
            int c = t >> 7, k = t & 127;
            float v = (c < 64) ? W2l[k * 64 + c] : W2r[k * 64 + (c - 64)];
            Bt2[c * 128 + k] = f2b(v);
        }
    }
}

// ---------------------------------------------------------------------------
// FULLY FUSED layer-1 + layer-2 transform, BM=64 rows/block (r14 config):
//  A: gather-mean 64 rows -> LDS [m1|x] (4-wide unroll, ushort cols)
//  B: C1 = A @ Bt1^T (K=256);  C: h=relu(C1+b1) -> Hs (LDS)
//  D: C2 = Hs @ Bt2^T (K=128); cols<64 -> hlb bf16; cols>=64 -> hrb bf16.
// ---------------------------------------------------------------------------
__global__ __launch_bounds__(256) void agg_gemm12(const unsigned short* __restrict__ xb,
                                                  const int* __restrict__ cursor,
                                                  const unsigned short* __restrict__ col,
                                                  const unsigned short* __restrict__ Bt1,
                                                  const unsigned short* __restrict__ Bt2,
                                                  const float* __restrict__ b1,
                                                  unsigned short* __restrict__ hlb,
                                                  unsigned short* __restrict__ hrb) {
    constexpr int LDA = 264;                       // 256 + 8 pad
    constexpr int LDH = 136;                       // 128 + 8 pad
    __shared__ unsigned short As[64 * LDA];        // 33.8 KB; Hs aliases front

    const int base = blockIdx.x * 64;
    const int tid  = threadIdx.x;
    const int l    = tid & 15;                     // 8 dims (16B) per lane
    const int sub  = tid >> 4;                     // 16 rows at a time

    const uint4* fp = reinterpret_cast<const uint4*>(xb);

    // ---- phase A: gather (4-wide unroll, ushort cols) ----
    for (int gq = 0; gq < 4; ++gq) {
        const int r  = gq * 16 + sub;              // 0..63
        const int gn = base + r;
        float a0 = 0.f, a1 = 0.f, a2 = 0.f, a3 = 0.f,
              a4 = 0.f, a5 = 0.f, a6 = 0.f, a7 = 0.f;
        uint4 xrow = make_uint4(0, 0, 0, 0);
        if (gn < NN) {
            int len = cursor[gn];
            len = (len > CAP) ? CAP : len;
            const unsigned short* cl = col + gn * CAP;
            int j = 0;
            for (; j + 4 <= len; j += 4) {
                u16x4 c4 = *reinterpret_cast<const u16x4*>(cl + j);
                uint4 v0 = fp[(int)c4[0] * 16 + l];
                uint4 v1 = fp[(int)c4[1] * 16 + l];
                uint4 v2 = fp[(int)c4[2] * 16 + l];
                uint4 v3 = fp[(int)c4[3] * 16 + l];
                a0 += (b2f_lo(v0.x) + b2f_lo(v1.x)) + (b2f_lo(v2.x) + b2f_lo(v3.x));
                a1 += (b2f_hi(v0.x) + b2f_hi(v1.x)) + (b2f_hi(v2.x) + b2f_hi(v3.x));
                a2 += (b2f_lo(v0.y) + b2f_lo(v1.y)) + (b2f_lo(v2.y) + b2f_lo(v3.y));
                a3 += (b2f_hi(v0.y) + b2f_hi(v1.y)) + (b2f_hi(v2.y) + b2f_hi(v3.y));
                a4 += (b2f_lo(v0.z) + b2f_lo(v1.z)) + (b2f_lo(v2.z) + b2f_lo(v3.z));
                a5 += (b2f_hi(v0.z) + b2f_hi(v1.z)) + (b2f_hi(v2.z) + b2f_hi(v3.z));
                a6 += (b2f_lo(v0.w) + b2f_lo(v1.w)) + (b2f_lo(v2.w) + b2f_lo(v3.w));
                a7 += (b2f_hi(v0.w) + b2f_hi(v1.w)) + (b2f_hi(v2.w) + b2f_hi(v3.w));
            }
            for (; j < len; ++j) {
                uint4 v0 = fp[(int)cl[j] * 16 + l];
                a0 += b2f_lo(v0.x);  a1 += b2f_hi(v0.x);
                a2 += b2f_lo(v0.y);  a3 += b2f_hi(v0.y);
                a4 += b2f_lo(v0.z);  a5 += b2f_hi(v0.z);
                a6 += b2f_lo(v0.w);  a7 += b2f_hi(v0.w);
            }
            const float inv = 1.0f / fmaxf((float)len, 1.0f);
            a0 *= inv; a1 *= inv; a2 *= inv; a3 *= inv;
            a4 *= inv; a5 *= inv; a6 *= inv; a7 *= inv;
            xrow = fp[gn * 16 + l];
        }
        uint4 u;
        u.x = (unsigned)f2b(a0) | ((unsigned)f2b(a1) << 16);
        u.y = (unsigned)f2b(a2) | ((unsigned)f2b(a3) << 16);
        u.z = (unsigned)f2b(a4) | ((unsigned)f2b(a5) << 16);
        u.w = (unsigned)f2b(a6) | ((unsigned)f2b(a7) << 16);
        *reinterpret_cast<uint4*>(&As[r * LDA + l * 8])       = u;
        *reinterpret_cast<uint4*>(&As[r * LDA + 128 + l * 8]) = xrow;
    }
    __syncthreads();

    const int wid  = tid >> 6, lane = tid & 63;
    const int lr   = lane & 15;
    const int lk   = (lane >> 4) * 8;
    const int ccol = lane & 15;
    const int ri   = (lane >> 4) * 4;

    // ---- phase B: GEMM1, K=256 ----
    f32x4 acc[4][2];
#pragma unroll
    for (int t = 0; t < 4; ++t) {
        acc[t][0] = (f32x4){0.f, 0.f, 0.f, 0.f};
        acc[t][1] = (f32x4){0.f, 0.f, 0.f, 0.f};
    }
    for (int ks = 0; ks < 8; ++ks) {
        const int k = ks * 32 + lk;
        bf16x8 b0 = *reinterpret_cast<const bf16x8*>(Bt1 + (size_t)(wid * 32 + lr) * 256 + k);
        bf16x8 b1 = *reinterpret_cast<const bf16x8*>(Bt1 + (size_t)(wid * 32 + 16 + lr) * 256 + k);
#pragma unroll
        for (int t = 0; t < 4; ++t) {
            bf16x8 a = *reinterpret_cast<const bf16x8*>(&As[(t * 16 + lr) * LDA + k]);
            acc[t][0] = __builtin_amdgcn_mfma_f32_16x16x32_bf16(a, b0, acc[t][0], 0, 0, 0);
            acc[t][1] = __builtin_amdgcn_mfma_f32_16x16x32_bf16(a, b1, acc[t][1], 0, 0, 0);
        }
    }
    __syncthreads();                               // all As reads complete

    // ---- phase C: h = relu(C1 + b1) -> Hs (reuse As memory) ----
    unsigned short* Hs = As;
#pragma unroll
    for (int t = 0; t < 4; ++t) {
#pragma unroll
        for (int f = 0; f < 2; ++f) {
            const int colg = wid * 32 + f * 16 + ccol;
            const float bv = b1[colg];
#pragma unroll
            for (int i = 0; i < 4; ++i) {
                Hs[(t * 16 + ri + i) * LDH + colg] = f2b(fmaxf(acc[t][f][i] + bv, 0.f));
            }
        }
    }
    __syncthreads();

    // ---- phase D: GEMM2, K=128 from Hs; B streamed from L2-hot Bt2 ----
    f32x4 acc2[4][2];
#pragma unroll
    for (int t = 0; t < 4; ++t) {
        acc2[t][0] = (f32x4){0.f, 0.f, 0.f, 0.f};
        acc2[t][1] = (f32x4){0.f, 0.f, 0.f, 0.f};
    }
    for (int ks = 0; ks < 4; ++ks) {
        const int k = ks * 32 + lk;
        bf16x8 b0 = *reinterpret_cast<const bf16x8*>(Bt2 + (size_t)(wid * 32 + lr) * 128 + k);
        bf16x8 b1 = *reinterpret_cast<const bf16x8*>(Bt2 + (size_t)(wid * 32 + 16 + lr) * 128 + k);
#pragma unroll
        for (int t = 0; t < 4; ++t) {
            bf16x8 a = *reinterpret_cast<const bf16x8*>(&Hs[(t * 16 + lr) * LDH + k]);
            acc2[t][0] = __builtin_amdgcn_mfma_f32_16x16x32_bf16(a, b0, acc2[t][0], 0, 0, 0);
            acc2[t][1] = __builtin_amdgcn_mfma_f32_16x16x32_bf16(a, b1, acc2[t][1], 0, 0, 0);
        }
    }

#pragma unroll
    for (int t = 0; t < 4; ++t) {
#pragma unroll
        for (int f = 0; f < 2; ++f) {
            const int colg = wid * 32 + f * 16 + ccol;
#pragma unroll
            for (int i = 0; i < 4; ++i) {
                const int gn = base + t * 16 + ri + i;
                if (gn < NN) {
                    float v = acc2[t][f][i];
                    if (colg < 64) hlb[(size_t)gn * 64 + colg] = f2b(v);
                    else           hrb[(size_t)gn * 64 + (colg - 64)] = f2b(v);
                }
            }
        }
    }
}

// ---------------------------------------------------------------------------
// layer-2 aggregation: out[n] = mean(hlb[nbrs]) + hrb[n] + b2.
// 8 lanes/node x 8 dims; ushort cols, 4-wide unroll. Writes d_out once.
// ---------------------------------------------------------------------------
__global__ __launch_bounds__(256) void agg2_kernel(const unsigned short* __restrict__ feat,
                                                   const int* __restrict__ cursor,
                                                   const unsigned short* __restrict__ col,
                                                   const unsigned short* __restrict__ hrb,
                                                   const float* __restrict__ b2,
                                                   float* __restrict__ outf) {
    const int n = blockIdx.x * 32 + (threadIdx.x >> 3);
    const int l = threadIdx.x & 7;
    if (n >= NN) return;
    int len = cursor[n];
    len = (len > CAP) ? CAP : len;
    float a0 = 0.f, a1 = 0.f, a2 = 0.f, a3 = 0.f, a4 = 0.f, a5 = 0.f, a6 = 0.f, a7 = 0.f;
    const uint4* fp = reinterpret_cast<const uint4*>(feat);
    const unsigned short* cl = col + n * CAP;

    int j = 0;
    for (; j + 4 <= len; j += 4) {
        u16x4 c4 = *reinterpret_cast<const u16x4*>(cl + j);
        uint4 v0 = fp[(int)c4[0] * 8 + l];
        uint4 v1 = fp[(int)c4[1] * 8 + l];
        uint4 v2 = fp[(int)c4[2] * 8 + l];
        uint4 v3 = fp[(int)c4[3] * 8 + l];
        a0 += (b2f_lo(v0.x) + b2f_lo(v1.x)) + (b2f_lo(v2.x) + b2f_lo(v3.x));
        a1 += (b2f_hi(v0.x) + b2f_hi(v1.x)) + (b2f_hi(v2.x) + b2f_hi(v3.x));
        a2 += (b2f_lo(v0.y) + b2f_lo(v1.y)) + (b2f_lo(v2.y) + b2f_lo(v3.y));
        a3 += (b2f_hi(v0.y) + b2f_hi(v1.y)) + (b2f_hi(v2.y) + b2f_hi(v3.y));
        a4 += (b2f_lo(v0.z) + b2f_lo(v1.z)) + (b2f_lo(v2.z) + b2f_lo(v3.z));
        a5 += (b2f_hi(v0.z) + b2f_hi(v1.z)) + (b2f_hi(v2.z) + b2f_hi(v3.z));
        a6 += (b2f_lo(v0.w) + b2f_lo(v1.w)) + (b2f_lo(v2.w) + b2f_lo(v3.w));
        a7 += (b2f_hi(v0.w) + b2f_hi(v1.w)) + (b2f_hi(v2.w) + b2f_hi(v3.w));
    }
    for (; j < len; ++j) {
        uint4 v0 = fp[(int)cl[j] * 8 + l];
        a0 += b2f_lo(v0.x);  a1 += b2f_hi(v0.x);
        a2 += b2f_lo(v0.y);  a3 += b2f_hi(v0.y);
        a4 += b2f_lo(v0.z);  a5 += b2f_hi(v0.z);
        a6 += b2f_lo(v0.w);  a7 += b2f_hi(v0.w);
    }
    const float inv = 1.0f / fmaxf((float)len, 1.0f);
    uint4 hv = reinterpret_cast<const uint4*>(hrb)[(size_t)n * 8 + l];
    const float4* bp = reinterpret_cast<const float4*>(b2 + l * 8);
    float4 bv0 = bp[0], bv1 = bp[1];
    float4 o0 = make_float4(a0 * inv + b2f_lo(hv.x) + bv0.x,
                            a1 * inv + b2f_hi(hv.x) + bv0.y,
                            a2 * inv + b2f_lo(hv.y) + bv0.z,
                            a3 * inv + b2f_hi(hv.y) + bv0.w);
    float4 o1 = make_float4(a4 * inv + b2f_lo(hv.z) + bv1.x,
                            a5 * inv + b2f_hi(hv.z) + bv1.y,
                            a6 * inv + b2f_lo(hv.w) + bv1.z,
                            a7 * inv + b2f_hi(hv.w) + bv1.w);
    float4* op = reinterpret_cast<float4*>(outf + (size_t)n * 64) + l * 2;
    op[0] = o0; op[1] = o1;
}

// ---------------------------------------------------------------------------
extern "C" void kernel_launch(void* const* d_in, const int* in_sizes, int n_in,
                              void* d_out, int out_size, void* d_ws, size_t ws_size,
                              hipStream_t stream) {
    const float* x   = (const float*)d_in[0];
    const int*   ei  = (const int*)d_in[1];
    const float* W1l = (const float*)d_in[2];
    const float* b1  = (const float*)d_in[3];
    const float* W1r = (const float*)d_in[4];
    const float* W2l = (const float*)d_in[5];
    const float* b2  = (const float*)d_in[6];
    const float* W2r = (const float*)d_in[7];

    const int* src = ei;
    const int* dst = ei + NE;

    // workspace layout (bytes), total ~48.3 MB:
    // [cursor NN]                  0         .. 200,000   (zeroed by prep tail blocks)
    // [bcnt 2048]                  200,000   .. 208,192
    // [col NN*CAP ushort]          208,384   .. 5,008,384
    // [xb  NN*128 bf16]            9,808,384 .. 22,608,384
    // [hlb NN*64 bf16]             22,608,384.. 29,008,384
    // [hrb NN*64 bf16]             29,008,384.. 35,408,384
    // [stage 8*256*SEG u32]        35,408,384.. 48,208,384  (dead after scatter)
    // [Bt1 128*256 bf16]           48,208,384.. 48,273,920
    // [Bt2 128*128 bf16]           48,273,920.. 48,306,688
    char* ws = (char*)d_ws;
    int* cursor = (int*)ws;
    int* bcnt   = (int*)(ws + 200000);
    unsigned short* col = (unsigned short*)(ws + 208384);
    unsigned short* xb  = (unsigned short*)(ws + 9808384);
    unsigned short* hlb = (unsigned short*)(ws + 22608384);
    unsigned short* hrb = (unsigned short*)(ws + 29008384);
    unsigned*       stage = (unsigned*)(ws + 35408384);
    unsigned short* Bt1 = (unsigned short*)(ws + 48208384);
    unsigned short* Bt2 = (unsigned short*)(ws + 48273920);
    float* outp = (float*)d_out;

    // bin + cursor-zero (cvt moved out of the critical prefix)
    prep_kernel<<<BIN_BLOCKS + ZERO_BLOCKS, 256, 0, stream>>>(src, dst, bcnt, stage,
                                                              cursor);
    // scatter (atomic-latency-bound) co-launched with cvt (streaming)
    scatter_kernel<<<SCAT_BLOCKS + CVT_BLOCKS, 256, 0, stream>>>(
        bcnt, stage, cursor, col, x, W1l, W1r, W2l, W2r, xb, Bt1, Bt2);

    // ----- fused layer-1 (gather + GEMM1 + relu) + layer-2 transform -----
    agg_gemm12<<<(NN + 63) / 64, 256, 0, stream>>>(xb, cursor, col, Bt1, Bt2,
                                                   b1, hlb, hrb);

    // ----- layer-2 aggregation (+ root path + b2), writes d_out once -----
    agg2_kernel<<<(NN + 31) / 32, 256, 0, stream>>>(hlb, cursor, col, hrb, b2, outp);
}